// Round 1
// baseline (1019.406 us; speedup 1.0000x reference)
//
#include <hip/hip_runtime.h>
#include <math.h>

#define NB 4096
#define NC 8192
#define ND 128

// ws layout (floats): [0]=loss_sum, [1]=tril_sum, [2]=pull_sum, [16..) xn[4096], then cn[8192]
#define WS_XN 16
#define WS_CN (16 + NB)

__global__ void init_ws_kernel(float* ws) {
  if (threadIdx.x < 16) ws[threadIdx.x] = 0.0f;
}

// one wave per row: xn / cn
__global__ __launch_bounds__(256) void norms_kernel(
    const float* __restrict__ x, const float* __restrict__ c, float* __restrict__ ws) {
  int wid = threadIdx.x >> 6, lane = threadIdx.x & 63;
  int row = blockIdx.x * 4 + wid;
  const float* src;
  float* dst;
  if (row < NB) {
    src = x + (size_t)row * ND;
    dst = ws + WS_XN + row;
  } else {
    int r = row - NB;
    if (r >= NC) return;
    src = c + (size_t)r * ND;
    dst = ws + WS_CN + r;
  }
  float2 v = *(const float2*)(src + lane * 2);
  float s = fmaf(v.x, v.x, v.y * v.y);
#pragma unroll
  for (int off = 32; off; off >>= 1) s += __shfl_down(s, off, 64);
  if (lane == 0) *dst = s;
}

#define DOT4(ac, av, bv)        \
  ac = fmaf(av.x, bv.x, ac);    \
  ac = fmaf(av.y, bv.y, ac);    \
  ac = fmaf(av.z, bv.z, ac);    \
  ac = fmaf(av.w, bv.w, ac);

// centers x centers^T distance tiles; upper-triangular blocks only, mirror via LDS transpose.
__global__ __launch_bounds__(256) void c2c_kernel(
    const float* __restrict__ centers, const float* __restrict__ ws,
    float* __restrict__ outmat, float* __restrict__ ws_acc) {
  int bi = blockIdx.x, bj = blockIdx.y;
  if (bi > bj) return;
  __shared__ float As[64][68];
  __shared__ float Bs[64][68];
  __shared__ float red[4];
  int t = threadIdx.x;
  const float* arow = centers + (size_t)bi * 64 * ND;
  const float* brow = centers + (size_t)bj * 64 * ND;

  int r0 = (t >> 4) << 2, c0 = (t & 15) << 2;
  float acc[16];
#pragma unroll
  for (int k = 0; k < 16; ++k) acc[k] = 0.0f;

  for (int kh = 0; kh < 2; ++kh) {
    if (kh) __syncthreads();
#pragma unroll
    for (int q = 0; q < 4; ++q) {
      int lin = t + 256 * q;            // 0..1023
      int m = lin >> 4, f4 = (lin & 15) << 2;
      *(float4*)&As[m][f4] = *(const float4*)(arow + m * ND + kh * 64 + f4);
      *(float4*)&Bs[m][f4] = *(const float4*)(brow + m * ND + kh * 64 + f4);
    }
    __syncthreads();
#pragma unroll 4
    for (int d = 0; d < 64; d += 4) {
      float4 a0 = *(const float4*)&As[r0 + 0][d];
      float4 a1 = *(const float4*)&As[r0 + 1][d];
      float4 a2 = *(const float4*)&As[r0 + 2][d];
      float4 a3 = *(const float4*)&As[r0 + 3][d];
      float4 b0 = *(const float4*)&Bs[c0 + 0][d];
      float4 b1 = *(const float4*)&Bs[c0 + 1][d];
      float4 b2 = *(const float4*)&Bs[c0 + 2][d];
      float4 b3 = *(const float4*)&Bs[c0 + 3][d];
      DOT4(acc[0], a0, b0)  DOT4(acc[1], a0, b1)  DOT4(acc[2], a0, b2)  DOT4(acc[3], a0, b3)
      DOT4(acc[4], a1, b0)  DOT4(acc[5], a1, b1)  DOT4(acc[6], a1, b2)  DOT4(acc[7], a1, b3)
      DOT4(acc[8], a2, b0)  DOT4(acc[9], a2, b1)  DOT4(acc[10], a2, b2) DOT4(acc[11], a2, b3)
      DOT4(acc[12], a3, b0) DOT4(acc[13], a3, b1) DOT4(acc[14], a3, b2) DOT4(acc[15], a3, b3)
    }
  }

  float ni[4], nj[4];
#pragma unroll
  for (int i = 0; i < 4; ++i) ni[i] = ws[WS_CN + bi * 64 + r0 + i];
#pragma unroll
  for (int j = 0; j < 4; ++j) nj[j] = ws[WS_CN + bj * 64 + c0 + j];

  float dreg[16];
  float tsum = 0.0f;
#pragma unroll
  for (int i = 0; i < 4; ++i) {
#pragma unroll
    for (int j = 0; j < 4; ++j) {
      float dd = ni[i] + nj[j] - 2.0f * acc[i * 4 + j];
      dd = fminf(fmaxf(dd, 1e-12f), 1e12f);
      dreg[i * 4 + j] = dd;
    }
  }
  if (bi == bj) {
#pragma unroll
    for (int i = 0; i < 4; ++i)
#pragma unroll
      for (int j = 0; j < 4; ++j)
        if (r0 + i > c0 + j) tsum += dreg[i * 4 + j];
  } else {
#pragma unroll
    for (int k = 0; k < 16; ++k) tsum += dreg[k];
  }

  // direct (upper) writes, float4 rows
#pragma unroll
  for (int i = 0; i < 4; ++i) {
    int gi = bi * 64 + r0 + i;
    float4 o = make_float4(dreg[i * 4 + 0], dreg[i * 4 + 1], dreg[i * 4 + 2], dreg[i * 4 + 3]);
    *(float4*)(outmat + (size_t)gi * NC + bj * 64 + c0) = o;
  }

  // tril partial-sum reduction -> one atomic per block
#pragma unroll
  for (int off = 32; off; off >>= 1) tsum += __shfl_down(tsum, off, 64);
  int lane = t & 63, wv = t >> 6;
  if (lane == 0) red[wv] = tsum;
  __syncthreads();   // also guards As reuse below
  if (t == 0) atomicAdd(ws_acc + 1, red[0] + red[1] + red[2] + red[3]);

  // mirror (lower) tile via LDS transpose, coalesced row writes
  if (bi != bj) {
    float* Ts = &As[0][0];  // 64 x 68 region, fits in As
#pragma unroll
    for (int i = 0; i < 4; ++i)
#pragma unroll
      for (int j = 0; j < 4; ++j)
        Ts[(c0 + j) * 68 + (r0 + i)] = dreg[i * 4 + j];
    __syncthreads();
#pragma unroll
    for (int w = 0; w < 4; ++w) {
      int lin = t + 256 * w;            // 0..1023
      int rr = lin >> 4, f4 = (lin & 15) << 2;
      *(float4*)(outmat + (size_t)(bj * 64 + rr) * NC + bi * 64 + f4) =
          *(const float4*)&Ts[rr * 68 + f4];
    }
  }
}

// fused x@centers^T + per-row top-10 (excl. label) + pos + LSE loss
__global__ __launch_bounds__(256) void xloss_kernel(
    const float* __restrict__ x, const int* __restrict__ labels,
    const float* __restrict__ centers, const float* __restrict__ ws,
    float* __restrict__ ws_acc) {
  __shared__ float xs[16][132];           // full-depth x rows
  __shared__ float cs[64][68];            // K-half of 64 centers
  __shared__ float mergebuf[16][16][10];
  __shared__ float posv[16];
  __shared__ float rowred[32];
  int t = threadIdx.x;
  int rowbase = blockIdx.x << 4;

#pragma unroll
  for (int q = 0; q < 2; ++q) {
    int lin = t + 256 * q;                // 0..511
    int m = lin >> 5, f4 = (lin & 31) << 2;
    *(float4*)&xs[m][f4] = *(const float4*)(x + (size_t)(rowbase + m) * ND + f4);
  }
  if (t < 16) posv[t] = 0.0f;

  int r = t >> 4, cl = t & 15;
  int c0 = cl << 2;
  int lab = labels[rowbase + r];
  float xn_r = ws[WS_XN + rowbase + r];

  float top[10];
#pragma unroll
  for (int k = 0; k < 10; ++k) top[k] = -3.0e38f;

  for (int tile = 0; tile < NC / 64; ++tile) {
    const float* cbase = centers + (size_t)tile * 64 * ND;
    float a0 = 0.f, a1 = 0.f, a2 = 0.f, a3 = 0.f;
    for (int kh = 0; kh < 2; ++kh) {
#pragma unroll
      for (int q = 0; q < 4; ++q) {
        int lin = t + 256 * q;            // 0..1023
        int m = lin >> 4, f4 = (lin & 15) << 2;
        *(float4*)&cs[m][f4] = *(const float4*)(cbase + m * ND + kh * 64 + f4);
      }
      __syncthreads();
#pragma unroll 4
      for (int d = 0; d < 64; d += 4) {
        float4 xv = *(const float4*)&xs[r][kh * 64 + d];
        float4 v0 = *(const float4*)&cs[c0 + 0][d];
        float4 v1 = *(const float4*)&cs[c0 + 1][d];
        float4 v2 = *(const float4*)&cs[c0 + 2][d];
        float4 v3 = *(const float4*)&cs[c0 + 3][d];
        DOT4(a0, xv, v0) DOT4(a1, xv, v1) DOT4(a2, xv, v2) DOT4(a3, xv, v3)
      }
      __syncthreads();                    // before next load overwrites cs
    }
    float dot[4] = {a0, a1, a2, a3};
#pragma unroll
    for (int j = 0; j < 4; ++j) {
      int gj = (tile << 6) + c0 + j;
      float dd = xn_r + ws[WS_CN + gj] - 2.0f * dot[j];
      dd = fminf(fmaxf(dd, 1e-12f), 1e12f);
      float s = -dd;
      if (gj == lab) {
        posv[r] = s;                      // single writer per row
      } else if (s > top[9]) {
        float v = s;
#pragma unroll
        for (int k = 0; k < 10; ++k) {    // static-index sorted insert
          float mx = fmaxf(top[k], v);
          v = fminf(top[k], v);
          top[k] = mx;
        }
      }
    }
  }

#pragma unroll
  for (int k = 0; k < 10; ++k) mergebuf[r][cl][k] = top[k];
  __syncthreads();

  if (t < 16) {
    float m10[10];
#pragma unroll
    for (int k = 0; k < 10; ++k) m10[k] = -3.0e38f;
    for (int cc = 0; cc < 16; ++cc) {
#pragma unroll
      for (int k = 0; k < 10; ++k) {
        float v = mergebuf[t][cc][k];
        if (v > m10[9]) {
          float vv = v;
#pragma unroll
          for (int q = 0; q < 10; ++q) {
            float mx = fmaxf(m10[q], vv);
            vv = fminf(m10[q], vv);
            m10[q] = mx;
          }
        }
      }
    }
    float pos = posv[t];
    float mx = fmaxf(pos, m10[0]);
    float ssum = expf(pos - mx);
#pragma unroll
    for (int k = 0; k < 10; ++k) ssum += expf(m10[k] - mx);
    float lse = mx + logf(ssum);
    rowred[t] = lse - pos;
    rowred[16 + t] = -pos;                // dist_pull = clipped dist = -pos
  }
  __syncthreads();
  if (t == 0) {
    float ls = 0.f, lp = 0.f;
#pragma unroll
    for (int k = 0; k < 16; ++k) { ls += rowred[k]; lp += rowred[16 + k]; }
    atomicAdd(ws_acc + 0, ls);
    atomicAdd(ws_acc + 2, lp);
  }
}

__global__ void finalize_kernel(const float* __restrict__ ws, float* __restrict__ out) {
  if (threadIdx.x == 0) {
    out[0] = ws[0] / 4096.0f;
    out[1] = -ws[1] / 33550336.0f;        // C*(C-1)/2 = 33550336
    out[2 + (size_t)NC * NC] = ws[2] / 4096.0f;
  }
}

extern "C" void kernel_launch(void* const* d_in, const int* in_sizes, int n_in,
                              void* d_out, int out_size, void* d_ws, size_t ws_size,
                              hipStream_t stream) {
  const float* x = (const float*)d_in[0];
  const int* labels = (const int*)d_in[1];
  const float* centers = (const float*)d_in[2];
  float* out = (float*)d_out;
  float* ws = (float*)d_ws;

  hipLaunchKernelGGL(init_ws_kernel, dim3(1), dim3(64), 0, stream, ws);
  hipLaunchKernelGGL(norms_kernel, dim3((NB + NC) / 4), dim3(256), 0, stream, x, centers, ws);
  hipLaunchKernelGGL(c2c_kernel, dim3(128, 128), dim3(256), 0, stream, centers, ws, out + 2, ws);
  hipLaunchKernelGGL(xloss_kernel, dim3(NB / 16), dim3(256), 0, stream, x, labels, centers, ws, ws);
  hipLaunchKernelGGL(finalize_kernel, dim3(1), dim3(64), 0, stream, ws, out);
}

// Round 2
// 185.466 us; speedup vs baseline: 5.4965x; 5.4965x over previous
//
#include <hip/hip_runtime.h>
#include <hip/hip_bf16.h>
#include <math.h>

#define NB 4096
#define NC 8192
#define ND 128
#define NSPLIT 16
#define CPS (NC / NSPLIT)          // 512 centers per split
#define NTILES (CPS / 16)          // 32 center-tiles per split

// ws layout (float offsets). Total = WS_CB + NC*ND/2 = 1,458,192 floats (~5.9 MB)
#define WS_XN 16
#define WS_CN (WS_XN + NB)                    // 4112
#define WS_POS (WS_CN + NC)                   // 12304
#define WS_PART (WS_POS + NB)                 // 16400, size NB*NSPLIT*10
#define WS_XB (WS_PART + NB * NSPLIT * 10)    // 671760, bf16 x as ushort[NB*ND]
#define WS_CB (WS_XB + NB * ND / 2)           // 933904, bf16 centers as ushort[NC*ND]

typedef __attribute__((ext_vector_type(8))) short short8v;   // 8 x bf16 frag
typedef __attribute__((ext_vector_type(4))) float f32x4;

__global__ void init_ws_kernel(float* ws) {
  if (threadIdx.x < 16) ws[threadIdx.x] = 0.0f;
}

// one wave per row: norm (f32) + bf16 conversion of x / centers
__global__ __launch_bounds__(256) void prep_kernel(
    const float* __restrict__ x, const float* __restrict__ c, float* __restrict__ ws) {
  int wid = threadIdx.x >> 6, lane = threadIdx.x & 63;
  int row = blockIdx.x * 4 + wid;
  const float* src;
  float* ndst;
  ushort* bdst;
  if (row < NB) {
    src = x + (size_t)row * ND;
    ndst = ws + WS_XN + row;
    bdst = (ushort*)(ws + WS_XB) + (size_t)row * ND;
  } else {
    int r = row - NB;
    src = c + (size_t)r * ND;
    ndst = ws + WS_CN + r;
    bdst = (ushort*)(ws + WS_CB) + (size_t)r * ND;
  }
  float2 v = *(const float2*)(src + lane * 2);
  __hip_bfloat16 h0 = __float2bfloat16(v.x);
  __hip_bfloat16 h1 = __float2bfloat16(v.y);
  ushort2 u;
  u.x = *(ushort*)&h0;
  u.y = *(ushort*)&h1;
  *(ushort2*)(bdst + lane * 2) = u;
  float s = fmaf(v.x, v.x, v.y * v.y);
#pragma unroll
  for (int off = 32; off; off >>= 1) s += __shfl_down(s, off, 64);
  if (lane == 0) *ndst = s;
}

#define INS10(arr, val)                          \
  {                                              \
    float _v = (val);                            \
    _Pragma("unroll") for (int _k = 0; _k < 10; ++_k) { \
      float _mx = fmaxf(arr[_k], _v);            \
      _v = fminf(arr[_k], _v);                   \
      arr[_k] = _mx;                             \
    }                                            \
  }

// fused x@centers^T (bf16 MFMA, swapped operands) + lane-local top-10 + pos capture
__global__ __launch_bounds__(256) void xloss_kernel(
    const int* __restrict__ labels, float* __restrict__ ws) {
  int t = threadIdx.x;
  int w = t >> 6, l = t & 63;
  int lo = l & 15, hi = l >> 4;
  int row = blockIdx.x * 64 + w * 16 + lo;
  int split = blockIdx.y;
  int cbase = split * CPS;

  const ushort* xb = (const ushort*)(ws + WS_XB);
  const ushort* cb = (const ushort*)(ws + WS_CB);

  // B-frags: x row 'row', k = ks*32 + hi*8 + i  (col = lane&15 = x-row)
  const ushort* xrp = xb + (size_t)row * ND + hi * 8;
  short8v xf0 = *(const short8v*)(xrp + 0);
  short8v xf1 = *(const short8v*)(xrp + 32);
  short8v xf2 = *(const short8v*)(xrp + 64);
  short8v xf3 = *(const short8v*)(xrp + 96);

  float xn = ws[WS_XN + row];
  int lab = labels[row];

  float top[10];
#pragma unroll
  for (int k = 0; k < 10; ++k) top[k] = -3.0e38f;
  float posv = -3.0e38f;

  for (int tl = 0; tl < NTILES; ++tl) {
    int c0 = cbase + tl * 16;
    const ushort* cp = cb + (size_t)(c0 + lo) * ND + hi * 8;   // A row = lane&15
    short8v a0 = *(const short8v*)(cp + 0);
    short8v a1 = *(const short8v*)(cp + 32);
    short8v a2 = *(const short8v*)(cp + 64);
    short8v a3 = *(const short8v*)(cp + 96);
    f32x4 acc = {0.f, 0.f, 0.f, 0.f};
    acc = __builtin_amdgcn_mfma_f32_16x16x32_bf16(a0, xf0, acc, 0, 0, 0);
    acc = __builtin_amdgcn_mfma_f32_16x16x32_bf16(a1, xf1, acc, 0, 0, 0);
    acc = __builtin_amdgcn_mfma_f32_16x16x32_bf16(a2, xf2, acc, 0, 0, 0);
    acc = __builtin_amdgcn_mfma_f32_16x16x32_bf16(a3, xf3, acc, 0, 0, 0);

    f32x4 cn4 = *(const f32x4*)(ws + WS_CN + c0 + hi * 4);
#pragma unroll
    for (int r = 0; r < 4; ++r) {
      int cidx = c0 + hi * 4 + r;
      float dist = xn + cn4[r] - 2.0f * acc[r];
      dist = fminf(fmaxf(dist, 1e-12f), 1e12f);
      float s = -dist;
      bool isl = (cidx == lab);
      posv = isl ? s : posv;
      float se = isl ? -3.0e38f : s;
      INS10(top, se)
    }
  }

  // merge partial top-10s across the 4 lane-groups holding the same x-row
  float oth[10];
#pragma unroll
  for (int m = 16; m <= 32; m <<= 1) {
#pragma unroll
    for (int k = 0; k < 10; ++k) oth[k] = __shfl_xor(top[k], m, 64);
#pragma unroll
    for (int k = 0; k < 10; ++k) INS10(top, oth[k])
  }

  if (posv > -1.0e37f) ws[WS_POS + row] = posv;   // single writer per row (global)
  if (hi == 0) {
    float* dst = ws + WS_PART + ((size_t)row * NSPLIT + split) * 10;
#pragma unroll
    for (int k = 0; k < 10; ++k) dst[k] = top[k];
  }
}

// per-row 16-way merge + LSE loss
__global__ __launch_bounds__(256) void merge_kernel(float* __restrict__ ws) {
  int row = blockIdx.x * 256 + threadIdx.x;
  const f32x4* part = (const f32x4*)(ws + WS_PART + (size_t)row * NSPLIT * 10);
  float top[10];
#pragma unroll
  for (int k = 0; k < 10; ++k) top[k] = -3.0e38f;
#pragma unroll
  for (int i = 0; i < NSPLIT * 10 / 4; ++i) {
    f32x4 v = part[i];
    INS10(top, v.x)
    INS10(top, v.y)
    INS10(top, v.z)
    INS10(top, v.w)
  }
  float pos = ws[WS_POS + row];
  float mx = fmaxf(pos, top[0]);
  float ssum = expf(pos - mx);
#pragma unroll
  for (int k = 0; k < 10; ++k) ssum += expf(top[k] - mx);
  float lrow = mx + logf(ssum) - pos;
  float prow = -pos;
#pragma unroll
  for (int off = 32; off; off >>= 1) {
    lrow += __shfl_down(lrow, off, 64);
    prow += __shfl_down(prow, off, 64);
  }
  if ((threadIdx.x & 63) == 0) {
    atomicAdd(ws + 0, lrow);
    atomicAdd(ws + 2, prow);
  }
}

// centers x centers^T via bf16 MFMA; full grid (both triangles), tril-sum fused
__global__ __launch_bounds__(256) void c2c_kernel(
    float* __restrict__ ws, float* __restrict__ outmat) {
  int bi = blockIdx.x, bj = blockIdx.y;
  int t = threadIdx.x;
  int w = t >> 6, l = t & 63, lo = l & 15, hi = l >> 4;
  int wm = w >> 1, wn = w & 1;
  int rowb = bi * 128 + wm * 64;
  int colb = bj * 128 + wn * 64;
  const ushort* cb = (const ushort*)(ws + WS_CB);

  f32x4 acc[4][4];
#pragma unroll
  for (int m = 0; m < 4; ++m)
#pragma unroll
    for (int n = 0; n < 4; ++n) acc[m][n] = (f32x4){0.f, 0.f, 0.f, 0.f};

#pragma unroll
  for (int ks = 0; ks < 4; ++ks) {
    short8v af[4], bf[4];
#pragma unroll
    for (int m = 0; m < 4; ++m)
      af[m] = *(const short8v*)(cb + (size_t)(rowb + m * 16 + lo) * ND + ks * 32 + hi * 8);
#pragma unroll
    for (int n = 0; n < 4; ++n)
      bf[n] = *(const short8v*)(cb + (size_t)(colb + n * 16 + lo) * ND + ks * 32 + hi * 8);
#pragma unroll
    for (int m = 0; m < 4; ++m)
#pragma unroll
      for (int n = 0; n < 4; ++n)
        acc[m][n] = __builtin_amdgcn_mfma_f32_16x16x32_bf16(af[m], bf[n], acc[m][n], 0, 0, 0);
  }

  float cnj[4];
#pragma unroll
  for (int n = 0; n < 4; ++n) cnj[n] = ws[WS_CN + colb + n * 16 + lo];
  float tsum = 0.0f;
#pragma unroll
  for (int m = 0; m < 4; ++m) {
    f32x4 cni = *(const f32x4*)(ws + WS_CN + rowb + m * 16 + hi * 4);
#pragma unroll
    for (int n = 0; n < 4; ++n) {
#pragma unroll
      for (int rr = 0; rr < 4; ++rr) {
        int gr = rowb + m * 16 + hi * 4 + rr;
        int gc = colb + n * 16 + lo;
        float dd = cni[rr] + cnj[n] - 2.0f * acc[m][n][rr];
        dd = fminf(fmaxf(dd, 1e-12f), 1e12f);
        outmat[(size_t)gr * NC + gc] = dd;
        if (bi > bj) tsum += dd;
        else if (bi == bj) tsum += (gr > gc) ? dd : 0.0f;
      }
    }
  }

  __shared__ float red[4];
#pragma unroll
  for (int off = 32; off; off >>= 1) tsum += __shfl_down(tsum, off, 64);
  if (l == 0) red[w] = tsum;
  __syncthreads();
  if (t == 0) atomicAdd(ws + 1, red[0] + red[1] + red[2] + red[3]);
}

__global__ void finalize_kernel(const float* __restrict__ ws, float* __restrict__ out) {
  if (threadIdx.x == 0) {
    out[0] = ws[0] / 4096.0f;
    out[1] = -ws[1] / 33550336.0f;        // C*(C-1)/2
    out[2 + (size_t)NC * NC] = ws[2] / 4096.0f;
  }
}

extern "C" void kernel_launch(void* const* d_in, const int* in_sizes, int n_in,
                              void* d_out, int out_size, void* d_ws, size_t ws_size,
                              hipStream_t stream) {
  const float* x = (const float*)d_in[0];
  const int* labels = (const int*)d_in[1];
  const float* centers = (const float*)d_in[2];
  float* out = (float*)d_out;
  float* ws = (float*)d_ws;

  hipLaunchKernelGGL(init_ws_kernel, dim3(1), dim3(64), 0, stream, ws);
  hipLaunchKernelGGL(prep_kernel, dim3((NB + NC) / 4), dim3(256), 0, stream, x, centers, ws);
  hipLaunchKernelGGL(c2c_kernel, dim3(64, 64), dim3(256), 0, stream, ws, out + 2);
  hipLaunchKernelGGL(xloss_kernel, dim3(64, NSPLIT), dim3(256), 0, stream, labels, ws);
  hipLaunchKernelGGL(merge_kernel, dim3(NB / 256), dim3(256), 0, stream, ws);
  hipLaunchKernelGGL(finalize_kernel, dim3(1), dim3(64), 0, stream, ws, out);
}

// Round 3
// 182.873 us; speedup vs baseline: 5.5744x; 1.0142x over previous
//
#include <hip/hip_runtime.h>
#include <hip/hip_bf16.h>
#include <math.h>

#define NB 4096
#define NC 8192
#define ND 128
#define NSPLIT 16
#define CPS (NC / NSPLIT)          // 512 centers per split
#define NTILES (CPS / 16)          // 32 center-tiles per split
#define XBLKS (64 * NSPLIT)        // 1024 xloss blocks

// ws layout (float offsets). [0]=loss_sum [1]=tril_sum [2]=pull_sum [3]=ticket
#define WS_XN 16
#define WS_CN (WS_XN + NB)                    // 4112
#define WS_POS (WS_CN + NC)                   // 12304
#define WS_PART (WS_POS + NB)                 // 16400, size NB*NSPLIT*10
#define WS_XB (WS_PART + NB * NSPLIT * 10)    // 671760, bf16 x as ushort[NB*ND]
#define WS_CB (WS_XB + NB * ND / 2)           // 933904, bf16 centers as ushort[NC*ND]

typedef __attribute__((ext_vector_type(8))) short short8v;   // 8 x bf16 frag
typedef __attribute__((ext_vector_type(4))) float f32x4;

// one wave per row: norm (f32) + bf16 conversion; block 0 zeroes accumulators
__global__ __launch_bounds__(256) void prep_kernel(
    const float* __restrict__ x, const float* __restrict__ c, float* __restrict__ ws) {
  if (blockIdx.x == 0 && threadIdx.x < 16) ws[threadIdx.x] = 0.0f;
  int wid = threadIdx.x >> 6, lane = threadIdx.x & 63;
  int row = blockIdx.x * 4 + wid;
  const float* src;
  float* ndst;
  ushort* bdst;
  if (row < NB) {
    src = x + (size_t)row * ND;
    ndst = ws + WS_XN + row;
    bdst = (ushort*)(ws + WS_XB) + (size_t)row * ND;
  } else {
    int r = row - NB;
    src = c + (size_t)r * ND;
    ndst = ws + WS_CN + r;
    bdst = (ushort*)(ws + WS_CB) + (size_t)r * ND;
  }
  float2 v = *(const float2*)(src + lane * 2);
  __hip_bfloat16 h0 = __float2bfloat16(v.x);
  __hip_bfloat16 h1 = __float2bfloat16(v.y);
  ushort2 u;
  u.x = *(ushort*)&h0;
  u.y = *(ushort*)&h1;
  *(ushort2*)(bdst + lane * 2) = u;
  float s = fmaf(v.x, v.x, v.y * v.y);
#pragma unroll
  for (int off = 32; off; off >>= 1) s += __shfl_down(s, off, 64);
  if (lane == 0) *ndst = s;
}

#define INS10(arr, val)                          \
  {                                              \
    float _v = (val);                            \
    _Pragma("unroll") for (int _k = 0; _k < 10; ++_k) { \
      float _mx = fmaxf(arr[_k], _v);            \
      _v = fminf(arr[_k], _v);                   \
      arr[_k] = _mx;                             \
    }                                            \
  }

// grid-fused: bids [0,XBLKS) = xloss (VALU-bound), rest = c2c (write-bound)
__global__ __launch_bounds__(256) void mega_kernel(
    const int* __restrict__ labels, float* __restrict__ ws, float* __restrict__ outmat) {
  int t = threadIdx.x;
  int w = t >> 6, l = t & 63, lo = l & 15, hi = l >> 4;
  int bid = blockIdx.x;

  if (bid < XBLKS) {
    // ---------------- xloss: x@centers^T MFMA (swapped) + lane-local top-10 ----------------
    int split = bid >> 6;
    int row = (bid & 63) * 64 + w * 16 + lo;
    int cbase = split * CPS;
    const ushort* xb = (const ushort*)(ws + WS_XB);
    const ushort* cb = (const ushort*)(ws + WS_CB);

    const ushort* xrp = xb + (size_t)row * ND + hi * 8;
    short8v xf0 = *(const short8v*)(xrp + 0);
    short8v xf1 = *(const short8v*)(xrp + 32);
    short8v xf2 = *(const short8v*)(xrp + 64);
    short8v xf3 = *(const short8v*)(xrp + 96);

    float xn = ws[WS_XN + row];
    int lab = labels[row];

    float top[10];
#pragma unroll
    for (int k = 0; k < 10; ++k) top[k] = -3.0e38f;
    float posv = -3.0e38f;

    for (int tl = 0; tl < NTILES; ++tl) {
      int c0 = cbase + tl * 16;
      const ushort* cp = cb + (size_t)(c0 + lo) * ND + hi * 8;
      short8v a0 = *(const short8v*)(cp + 0);
      short8v a1 = *(const short8v*)(cp + 32);
      short8v a2 = *(const short8v*)(cp + 64);
      short8v a3 = *(const short8v*)(cp + 96);
      f32x4 acc = {0.f, 0.f, 0.f, 0.f};
      acc = __builtin_amdgcn_mfma_f32_16x16x32_bf16(a0, xf0, acc, 0, 0, 0);
      acc = __builtin_amdgcn_mfma_f32_16x16x32_bf16(a1, xf1, acc, 0, 0, 0);
      acc = __builtin_amdgcn_mfma_f32_16x16x32_bf16(a2, xf2, acc, 0, 0, 0);
      acc = __builtin_amdgcn_mfma_f32_16x16x32_bf16(a3, xf3, acc, 0, 0, 0);

      f32x4 cn4 = *(const f32x4*)(ws + WS_CN + c0 + hi * 4);
#pragma unroll
      for (int r = 0; r < 4; ++r) {
        int cidx = c0 + hi * 4 + r;
        float dist = xn + cn4[r] - 2.0f * acc[r];
        dist = fminf(fmaxf(dist, 1e-12f), 1e12f);
        float s = -dist;
        bool isl = (cidx == lab);
        posv = isl ? s : posv;
        float se = isl ? -3.0e38f : s;
        INS10(top, se)
      }
    }

    float oth[10];
#pragma unroll
    for (int m = 16; m <= 32; m <<= 1) {
#pragma unroll
      for (int k = 0; k < 10; ++k) oth[k] = __shfl_xor(top[k], m, 64);
#pragma unroll
      for (int k = 0; k < 10; ++k) INS10(top, oth[k])
    }

    if (posv > -1.0e37f) ws[WS_POS + row] = posv;
    if (hi == 0) {
      float* dst = ws + WS_PART + ((size_t)row * NSPLIT + split) * 10;
#pragma unroll
      for (int k = 0; k < 10; ++k) dst[k] = top[k];
    }
  } else {
    // ---------------- c2c: centers x centers^T distances + fused tril-sum ----------------
    int bid2 = bid - XBLKS;
    int bi = bid2 >> 6, bj = bid2 & 63;
    int wm = w >> 1, wn = w & 1;
    int rowb = bi * 128 + wm * 64;
    int colb = bj * 128 + wn * 64;
    const ushort* cb = (const ushort*)(ws + WS_CB);

    f32x4 acc[4][4];
#pragma unroll
    for (int m = 0; m < 4; ++m)
#pragma unroll
      for (int n = 0; n < 4; ++n) acc[m][n] = (f32x4){0.f, 0.f, 0.f, 0.f};

#pragma unroll
    for (int ks = 0; ks < 4; ++ks) {
      short8v af[4], bf[4];
#pragma unroll
      for (int m = 0; m < 4; ++m)
        af[m] = *(const short8v*)(cb + (size_t)(rowb + m * 16 + lo) * ND + ks * 32 + hi * 8);
#pragma unroll
      for (int n = 0; n < 4; ++n)
        bf[n] = *(const short8v*)(cb + (size_t)(colb + n * 16 + lo) * ND + ks * 32 + hi * 8);
#pragma unroll
      for (int m = 0; m < 4; ++m)
#pragma unroll
        for (int n = 0; n < 4; ++n)
          acc[m][n] = __builtin_amdgcn_mfma_f32_16x16x32_bf16(af[m], bf[n], acc[m][n], 0, 0, 0);
    }

    float cnj[4];
#pragma unroll
    for (int n = 0; n < 4; ++n) cnj[n] = ws[WS_CN + colb + n * 16 + lo];
    float tsum = 0.0f;
#pragma unroll
    for (int m = 0; m < 4; ++m) {
      f32x4 cni = *(const f32x4*)(ws + WS_CN + rowb + m * 16 + hi * 4);
#pragma unroll
      for (int n = 0; n < 4; ++n) {
#pragma unroll
        for (int rr = 0; rr < 4; ++rr) {
          int gr = rowb + m * 16 + hi * 4 + rr;
          int gc = colb + n * 16 + lo;
          float dd = cni[rr] + cnj[n] - 2.0f * acc[m][n][rr];
          dd = fminf(fmaxf(dd, 1e-12f), 1e12f);
          outmat[(size_t)gr * NC + gc] = dd;
          if (bi > bj) tsum += dd;
          else if (bi == bj) tsum += (gr > gc) ? dd : 0.0f;
        }
      }
    }

    __shared__ float red[4];
#pragma unroll
    for (int off = 32; off; off >>= 1) tsum += __shfl_down(tsum, off, 64);
    if (l == 0) red[w] = tsum;
    __syncthreads();
    if (t == 0) atomicAdd(ws + 1, red[0] + red[1] + red[2] + red[3]);
  }
}

// per-row 16-way merge + LSE; last block (device ticket) finalizes scalars
__global__ __launch_bounds__(256) void merge_fin_kernel(float* __restrict__ ws,
                                                        float* __restrict__ out) {
  int row = blockIdx.x * 256 + threadIdx.x;
  const f32x4* part = (const f32x4*)(ws + WS_PART + (size_t)row * NSPLIT * 10);
  float top[10];
#pragma unroll
  for (int k = 0; k < 10; ++k) top[k] = -3.0e38f;
#pragma unroll
  for (int i = 0; i < NSPLIT * 10 / 4; ++i) {
    f32x4 v = part[i];
    INS10(top, v.x)
    INS10(top, v.y)
    INS10(top, v.z)
    INS10(top, v.w)
  }
  float pos = ws[WS_POS + row];
  float mx = fmaxf(pos, top[0]);
  float ssum = expf(pos - mx);
#pragma unroll
  for (int k = 0; k < 10; ++k) ssum += expf(top[k] - mx);
  float lrow = mx + logf(ssum) - pos;
  float prow = -pos;
#pragma unroll
  for (int off = 32; off; off >>= 1) {
    lrow += __shfl_down(lrow, off, 64);
    prow += __shfl_down(prow, off, 64);
  }
  if ((threadIdx.x & 63) == 0) {
    atomicAdd(ws + 0, lrow);
    atomicAdd(ws + 2, prow);
  }
  __syncthreads();
  if (threadIdx.x == 0) {
    __threadfence();
    unsigned tk = atomicAdd((unsigned int*)(ws + 3), 1u);
    if (tk == 15u) {
      float ls = atomicAdd(ws + 0, 0.0f);   // device-scope acquire-ish reads
      float ts = atomicAdd(ws + 1, 0.0f);
      float ps = atomicAdd(ws + 2, 0.0f);
      out[0] = ls / 4096.0f;
      out[1] = -ts / 33550336.0f;           // C*(C-1)/2
      out[2 + (size_t)NC * NC] = ps / 4096.0f;
    }
  }
}

extern "C" void kernel_launch(void* const* d_in, const int* in_sizes, int n_in,
                              void* d_out, int out_size, void* d_ws, size_t ws_size,
                              hipStream_t stream) {
  const float* x = (const float*)d_in[0];
  const int* labels = (const int*)d_in[1];
  const float* centers = (const float*)d_in[2];
  float* out = (float*)d_out;
  float* ws = (float*)d_ws;

  hipLaunchKernelGGL(prep_kernel, dim3((NB + NC) / 4), dim3(256), 0, stream, x, centers, ws);
  hipLaunchKernelGGL(mega_kernel, dim3(XBLKS + 64 * 64), dim3(256), 0, stream, labels, ws, out + 2);
  hipLaunchKernelGGL(merge_fin_kernel, dim3(NB / 256), dim3(256), 0, stream, ws, out);
}